// Round 1
// baseline (41.629 us; speedup 1.0000x reference)
//
#include <hip/hip_runtime.h>

// Reference: x (16,1,128,128) f32; out (16,1,2048,2048) f32.
// out[0,0] = nearest-neighbor 16x16 upsample of x[0,0]; rest zero.

#define OUT_H 2048
#define OUT_W 2048
#define SRC_W 128

__global__ void upsample_fill(const float* __restrict__ x, float4* __restrict__ out) {
    // Covers 2048*2048 floats = 1,048,576 float4 stores.
    int tid = blockIdx.x * blockDim.x + threadIdx.x;  // 0 .. 2^20-1
    int e = tid << 2;                                  // element index in image 0
    int r = e >> 11;                                   // row 0..2047  (2048 = 2^11)
    int c = e & (OUT_W - 1);                           // col, 4-aligned
    // 4 consecutive cols from a 4-aligned base never cross a 16-boundary,
    // so one source element covers the whole float4.
    float v = x[(r >> 4) * SRC_W + (c >> 4)];
    out[tid] = make_float4(v, v, v, v);
}

extern "C" void kernel_launch(void* const* d_in, const int* in_sizes, int n_in,
                              void* d_out, int out_size, void* d_ws, size_t ws_size,
                              hipStream_t stream) {
    const float* x = (const float*)d_in[0];
    float* out = (float*)d_out;

    const size_t img = (size_t)OUT_H * OUT_W;  // 4,194,304 floats = 16 MB

    // Zero images 1..15 (240 MB) with the HW fill path.
    hipMemsetAsync(out + img, 0, ((size_t)out_size - img) * sizeof(float), stream);

    // Fill image 0 with the upsample: 1M float4 stores.
    const int n4 = (int)(img / 4);             // 1,048,576
    upsample_fill<<<n4 / 256, 256, 0, stream>>>(x, (float4*)out);
}

// Round 2
// 39.171 us; speedup vs baseline: 1.0627x; 1.0627x over previous
//
#include <hip/hip_runtime.h>

// Reference: x (16,1,128,128) f32; out (16,1,2048,2048) f32.
// out[0,0] = nearest-neighbor 16x16 upsample of x[0,0]; rest zero.
// Single fused kernel: every thread stores one float4 of the 256 MB output.

#define OUT_W 2048
#define SRC_W 128
#define IMG0_F4 (2048 * 2048 / 4)   // 1,048,576 float4 in image 0

__global__ void fill_all(const float* __restrict__ x, float4* __restrict__ out) {
    int tid = blockIdx.x * blockDim.x + threadIdx.x;  // 0 .. 16,777,215
    float4 v4 = make_float4(0.f, 0.f, 0.f, 0.f);
    if (tid < IMG0_F4) {
        int e = tid << 2;                  // element index in image 0
        int r = e >> 11;                   // row (2048 = 2^11)
        int c = e & (OUT_W - 1);           // col, 4-aligned
        // 4-aligned float4 never crosses a 16-element upsample cell boundary,
        // so one source element covers the whole float4.
        float v = x[(r >> 4) * SRC_W + (c >> 4)];
        v4 = make_float4(v, v, v, v);
    }
    out[tid] = v4;
}

extern "C" void kernel_launch(void* const* d_in, const int* in_sizes, int n_in,
                              void* d_out, int out_size, void* d_ws, size_t ws_size,
                              hipStream_t stream) {
    const float* x = (const float*)d_in[0];
    float4* out = (float4*)d_out;

    const int n4 = out_size / 4;           // 16,777,216 float4 stores
    fill_all<<<n4 / 256, 256, 0, stream>>>(x, out);
}